// Round 3
// baseline (658.608 us; speedup 1.0000x reference)
//
#include <hip/hip_runtime.h>

#define HW 65536
#define NOUT 81     // 9 mask + 4*18 off
#define NFEAT 192   // 144 patch + 48 passthrough

// ---------------------------------------------------------------------------
// Setup: collapse (conv3x3 -> 1x1) into a single 192->81 linear map.
// ---------------------------------------------------------------------------
__global__ __launch_bounds__(256) void setup_weights(
    const float* __restrict__ off_pconv_w,  // (4,16,16,3,3)
    const float* __restrict__ off_w,        // (4,18,64)
    const float* __restrict__ off_b,        // (4,18)
    const float* __restrict__ mask_pconv_w, // (16,16,3,3)
    const float* __restrict__ mask_w,       // (9,64)
    const float* __restrict__ mask_b,       // (9,)
    float* __restrict__ Wt,                 // (192,81)
    float* __restrict__ bias)               // (81,)
{
    int id = blockIdx.x * 256 + threadIdx.x;
    const float PTS[18] = {-1,-1, -1,0, -1,1, 0,-1, 0,0, 0,1, 1,-1, 1,0, 1,1};
    if (id < NFEAT * NOUT) {
        int f = id / NOUT;
        int o = id % NOUT;
        float v;
        if (f < 144) {
            int p = f >> 4, c = f & 15;
            float s = 0.f;
            if (o < 9) {
                for (int cm = 0; cm < 16; ++cm)
                    s += mask_w[o * 64 + cm] * mask_pconv_w[(cm * 16 + c) * 9 + p];
            } else {
                int oo = o - 9, i = oo / 18, j = oo % 18;
                for (int cm = 0; cm < 16; ++cm)
                    s += off_w[(i * 18 + j) * 64 + cm] * off_pconv_w[((i * 16 + cm) * 16 + c) * 9 + p];
            }
            v = s;
        } else {
            int c = f - 144;
            if (o < 9) v = mask_w[o * 64 + 16 + c];
            else { int oo = o - 9, i = oo / 18, j = oo % 18; v = off_w[(i * 18 + j) * 64 + 16 + c]; }
        }
        Wt[id] = v;
    } else if (id < NFEAT * NOUT + NOUT) {
        int o = id - NFEAT * NOUT;
        float v;
        if (o < 9) v = mask_b[o];
        else {
            int oo = o - 9, i = oo / 18, j = oo % 18;
            v = off_b[i * 18 + j] + PTS[j] * (float)(2 * i + 1);
        }
        bias[o] = v;
    }
}

// ---------------------------------------------------------------------------
// Kernel 1: per-pixel 192-feature x 81-output linear map (the fused convs).
// ---------------------------------------------------------------------------
__global__ __launch_bounds__(256) void conv_offsets(
    const float* __restrict__ x,     // (2,64,256,256)
    const float* __restrict__ Wt,    // (192,81)
    const float* __restrict__ bias,  // (81,)
    float* __restrict__ mask_ws,     // (2,9,HW)
    float* __restrict__ off_ws)      // (2,72,HW)
{
    int gid = blockIdx.x * 256 + threadIdx.x;   // 131072 threads
    int b = gid >> 16;
    int pix = gid & 65535;
    int h = pix >> 8, w = pix & 255;

    float acc[NOUT];
#pragma unroll
    for (int o = 0; o < NOUT; ++o) acc[o] = bias[o];

    const float* xb = x + (size_t)b * 64 * HW;

    for (int p = 0; p < 9; ++p) {
        int hh = h + p / 3 - 1;
        int ww = w + p % 3 - 1;
        bool valid = ((unsigned)hh < 256u) && ((unsigned)ww < 256u);
        int poff = hh * 256 + ww;
        const float* wbase = Wt + p * 16 * NOUT;
        for (int c = 0; c < 16; ++c) {
            float xv = 0.f;
            if (valid) xv = xb[c * HW + poff];
            const float* wr = wbase + c * NOUT;
#pragma unroll
            for (int o = 0; o < NOUT; ++o) acc[o] = fmaf(xv, wr[o], acc[o]);
        }
    }
    for (int c = 0; c < 48; ++c) {
        float xv = xb[(16 + c) * HW + pix];
        const float* wr = Wt + (144 + c) * NOUT;
#pragma unroll
        for (int o = 0; o < NOUT; ++o) acc[o] = fmaf(xv, wr[o], acc[o]);
    }

#pragma unroll
    for (int k = 0; k < 9; ++k)
        mask_ws[(b * 9 + k) * HW + pix] = acc[k];
#pragma unroll
    for (int t = 0; t < 72; ++t)
        off_ws[(b * 72 + t) * HW + pix] = acc[9 + t];
}

// ---------------------------------------------------------------------------
// Transpose y (4,64,HW) -> T[(t*8+z)][pix][16c]  (channels innermost, 64B units)
// z = xb*4+i selects y[xb, i*16 .. i*16+15] (t=0) / y[xb+2, ...] (t=1).
// ---------------------------------------------------------------------------
__global__ __launch_bounds__(256) void transpose_y(
    const float* __restrict__ y, float* __restrict__ T)
{
    int bid = blockIdx.x;            // 2048
    int z = bid & 7, pr = bid >> 3;  // pr = row
    int pix = pr * 256 + threadIdx.x;
    int xb = z >> 2, i = z & 3;

    const float* p1 = y + (size_t)(xb * 64 + i * 16) * HW + pix;
    const float* p2 = y + (size_t)((xb + 2) * 64 + i * 16) * HW + pix;

    float v[16];
#pragma unroll
    for (int c = 0; c < 16; ++c) v[c] = p1[(size_t)c * HW];
    float4* dst = (float4*)(T + ((size_t)z * HW + pix) * 16);
#pragma unroll
    for (int j = 0; j < 4; ++j)
        dst[j] = make_float4(v[4 * j], v[4 * j + 1], v[4 * j + 2], v[4 * j + 3]);

#pragma unroll
    for (int c = 0; c < 16; ++c) v[c] = p2[(size_t)c * HW];
    dst = (float4*)(T + ((size_t)(8 + z) * HW + pix) * 16);
#pragma unroll
    for (int j = 0; j < 4; ++j)
        dst[j] = make_float4(v[4 * j], v[4 * j + 1], v[4 * j + 2], v[4 * j + 3]);
}

// ---------------------------------------------------------------------------
// Kernel 2 (fast path): per-(z,pixel) thread, loop over all 9 k in-thread.
// Gathers are 4x float4 (64B) from channel-innermost T; all 9 k reuse the
// same L2-resident slice. z = bid&7 pins each z to one XCD.
// ---------------------------------------------------------------------------
__global__ __launch_bounds__(256) void warp_apply_t(
    const float* __restrict__ T,        // (16,HW,16)
    const float* __restrict__ mask_ws,  // (2,9,HW)
    const float* __restrict__ off_ws,   // (2,72,HW)
    float* __restrict__ out)            // (4,64,9,256,256)
{
    int bid = blockIdx.x;            // 2048
    int z = bid & 7, h = bid >> 3;
    int w = threadIdx.x;
    int pix = h * 256 + w;
    int xb = z >> 2, i = z & 3;

    const float* T1 = T + (size_t)z * HW * 16;
    const float* T2 = T + (size_t)(8 + z) * HW * 16;

#pragma unroll 1
    for (int k = 0; k < 9; ++k) {
        float ox = off_ws[(size_t)(z * 18 + 2 * k) * HW + pix];
        float oy = off_ws[(size_t)(z * 18 + 2 * k + 1) * HW + pix];
        float m  = mask_ws[(size_t)(xb * 9 + k) * HW + pix];

        float px = fminf(fmaxf((float)w + ox, 0.f), 255.f);
        float py = fminf(fmaxf((float)h + oy, 0.f), 255.f);
        float x0f = floorf(px), y0f = floorf(py);
        float wx = px - x0f, wy = py - y0f;
        int x0 = (int)x0f, y0 = (int)y0f;
        int x1 = min(x0 + 1, 255), y1 = min(y0 + 1, 255);

        float w00 = (1.f - wx) * (1.f - wy) * m;
        float w01 = wx * (1.f - wy) * m;
        float w10 = (1.f - wx) * wy * m;
        float w11 = wx * wy * m;

        size_t o00 = (size_t)(y0 * 256 + x0) * 16;
        size_t o01 = (size_t)(y0 * 256 + x1) * 16;
        size_t o10 = (size_t)(y1 * 256 + x0) * 16;
        size_t o11 = (size_t)(y1 * 256 + x1) * 16;

#pragma unroll
        for (int t = 0; t < 2; ++t) {
            const float* Tt = t ? T2 : T1;
            const float4* A = (const float4*)(Tt + o00);
            const float4* B = (const float4*)(Tt + o01);
            const float4* C = (const float4*)(Tt + o10);
            const float4* D = (const float4*)(Tt + o11);

            float acc[16];
#pragma unroll
            for (int j = 0; j < 4; ++j) {
                float4 a = A[j];
                acc[4 * j]     = w00 * a.x;
                acc[4 * j + 1] = w00 * a.y;
                acc[4 * j + 2] = w00 * a.z;
                acc[4 * j + 3] = w00 * a.w;
            }
#pragma unroll
            for (int j = 0; j < 4; ++j) {
                float4 b = B[j];
                acc[4 * j]     = fmaf(w01, b.x, acc[4 * j]);
                acc[4 * j + 1] = fmaf(w01, b.y, acc[4 * j + 1]);
                acc[4 * j + 2] = fmaf(w01, b.z, acc[4 * j + 2]);
                acc[4 * j + 3] = fmaf(w01, b.w, acc[4 * j + 3]);
            }
#pragma unroll
            for (int j = 0; j < 4; ++j) {
                float4 c = C[j];
                acc[4 * j]     = fmaf(w10, c.x, acc[4 * j]);
                acc[4 * j + 1] = fmaf(w10, c.y, acc[4 * j + 1]);
                acc[4 * j + 2] = fmaf(w10, c.z, acc[4 * j + 2]);
                acc[4 * j + 3] = fmaf(w10, c.w, acc[4 * j + 3]);
            }
#pragma unroll
            for (int j = 0; j < 4; ++j) {
                float4 d = D[j];
                acc[4 * j]     = fmaf(w11, d.x, acc[4 * j]);
                acc[4 * j + 1] = fmaf(w11, d.y, acc[4 * j + 1]);
                acc[4 * j + 2] = fmaf(w11, d.z, acc[4 * j + 2]);
                acc[4 * j + 3] = fmaf(w11, d.w, acc[4 * j + 3]);
            }

            float* ob = out + ((size_t)((xb + 2 * t) * 64 + i * 16) * 9 + k) * HW + pix;
#pragma unroll
            for (int c = 0; c < 16; ++c)
                ob[(size_t)c * 9 * HW] = acc[c];
        }
    }
}

// ---------------------------------------------------------------------------
// Fallback (round-2 kernel) if workspace is too small for T.
// ---------------------------------------------------------------------------
__global__ __launch_bounds__(256) void warp_apply(
    const float* __restrict__ y,
    const float* __restrict__ mask_ws,
    const float* __restrict__ off_ws,
    float* __restrict__ out)
{
    int w = threadIdx.x;
    int h = blockIdx.x;
    int k = blockIdx.y;
    int z = blockIdx.z;
    int xb = z >> 2, i = z & 3;
    int pix = h * 256 + w;

    float ox = off_ws[(size_t)(z * 18 + 2 * k) * HW + pix];
    float oy = off_ws[(size_t)(z * 18 + 2 * k + 1) * HW + pix];
    float m  = mask_ws[(size_t)(xb * 9 + k) * HW + pix];

    float px = fminf(fmaxf((float)w + ox, 0.f), 255.f);
    float py = fminf(fmaxf((float)h + oy, 0.f), 255.f);
    float x0f = floorf(px), y0f = floorf(py);
    float wx = px - x0f, wy = py - y0f;
    int x0 = (int)x0f, y0 = (int)y0f;
    int x1 = min(x0 + 1, 255), y1 = min(y0 + 1, 255);

    float w00 = (1.f - wx) * (1.f - wy) * m;
    float w01 = wx * (1.f - wy) * m;
    float w10 = (1.f - wx) * wy * m;
    float w11 = wx * wy * m;

    int o00 = y0 * 256 + x0, o01 = y0 * 256 + x1;
    int o10 = y1 * 256 + x0, o11 = y1 * 256 + x1;

    const float* p1 = y + (size_t)(xb * 64 + i * 16) * HW;
    const float* p2 = y + (size_t)((xb + 2) * 64 + i * 16) * HW;
    float* out1 = out + ((size_t)(xb * 64 + i * 16) * 9 + k) * HW + pix;
    float* out2 = out + ((size_t)((xb + 2) * 64 + i * 16) * 9 + k) * HW + pix;

#pragma unroll
    for (int c = 0; c < 16; ++c) {
        const float* q = p1 + (size_t)c * HW;
        float v = w00 * q[o00] + w01 * q[o01] + w10 * q[o10] + w11 * q[o11];
        out1[(size_t)c * 9 * HW] = v;
        q = p2 + (size_t)c * HW;
        v = w00 * q[o00] + w01 * q[o01] + w10 * q[o10] + w11 * q[o11];
        out2[(size_t)c * 9 * HW] = v;
    }
}

// ---------------------------------------------------------------------------
extern "C" void kernel_launch(void* const* d_in, const int* in_sizes, int n_in,
                              void* d_out, int out_size, void* d_ws, size_t ws_size,
                              hipStream_t stream) {
    const float* x            = (const float*)d_in[0];
    const float* y            = (const float*)d_in[1];
    const float* off_pconv_w  = (const float*)d_in[2];
    const float* off_w        = (const float*)d_in[3];
    const float* off_b        = (const float*)d_in[4];
    const float* mask_pconv_w = (const float*)d_in[5];
    const float* mask_w       = (const float*)d_in[6];
    const float* mask_b       = (const float*)d_in[7];
    float* out = (float*)d_out;

    // ws layout (f32): [Wt+bias: 64KB] [mask: 4.7MB] [off: 37.7MB] [T: 67.1MB]
    float* Wt      = (float*)d_ws;
    float* bias    = Wt + NFEAT * NOUT;
    float* mask_ws = (float*)((char*)d_ws + 65536);
    float* off_ws  = mask_ws + (size_t)2 * 9 * HW;
    float* T       = off_ws + (size_t)2 * 72 * HW;

    size_t need = 65536 + (size_t)2 * 9 * HW * 4 + (size_t)2 * 72 * HW * 4
                + (size_t)16 * HW * 16 * 4;

    setup_weights<<<62, 256, 0, stream>>>(off_pconv_w, off_w, off_b,
                                          mask_pconv_w, mask_w, mask_b, Wt, bias);
    conv_offsets<<<512, 256, 0, stream>>>(x, Wt, bias, mask_ws, off_ws);

    if (ws_size >= need) {
        transpose_y<<<2048, 256, 0, stream>>>(y, T);
        warp_apply_t<<<2048, 256, 0, stream>>>(T, mask_ws, off_ws, out);
    } else {
        dim3 g2(256, 9, 8);
        warp_apply<<<g2, 256, 0, stream>>>(y, mask_ws, off_ws, out);
    }
}

// Round 4
// 640.447 us; speedup vs baseline: 1.0284x; 1.0284x over previous
//
#include <hip/hip_runtime.h>

#define HW 65536
#define NOUT 81     // 9 mask + 4*18 off
#define NFEAT 192   // 144 patch + 48 passthrough

// ---------------------------------------------------------------------------
// Setup: collapse (conv3x3 -> 1x1) into a single 192->81 linear map.
// ---------------------------------------------------------------------------
__global__ __launch_bounds__(256) void setup_weights(
    const float* __restrict__ off_pconv_w,  // (4,16,16,3,3)
    const float* __restrict__ off_w,        // (4,18,64)
    const float* __restrict__ off_b,        // (4,18)
    const float* __restrict__ mask_pconv_w, // (16,16,3,3)
    const float* __restrict__ mask_w,       // (9,64)
    const float* __restrict__ mask_b,       // (9,)
    float* __restrict__ Wt,                 // (192,81)
    float* __restrict__ bias)               // (81,)
{
    int id = blockIdx.x * 256 + threadIdx.x;
    const float PTS[18] = {-1,-1, -1,0, -1,1, 0,-1, 0,0, 0,1, 1,-1, 1,0, 1,1};
    if (id < NFEAT * NOUT) {
        int f = id / NOUT;
        int o = id % NOUT;
        float v;
        if (f < 144) {
            int p = f >> 4, c = f & 15;
            float s = 0.f;
            if (o < 9) {
                for (int cm = 0; cm < 16; ++cm)
                    s += mask_w[o * 64 + cm] * mask_pconv_w[(cm * 16 + c) * 9 + p];
            } else {
                int oo = o - 9, i = oo / 18, j = oo % 18;
                for (int cm = 0; cm < 16; ++cm)
                    s += off_w[(i * 18 + j) * 64 + cm] * off_pconv_w[((i * 16 + cm) * 16 + c) * 9 + p];
            }
            v = s;
        } else {
            int c = f - 144;
            if (o < 9) v = mask_w[o * 64 + 16 + c];
            else { int oo = o - 9, i = oo / 18, j = oo % 18; v = off_w[(i * 18 + j) * 64 + 16 + c]; }
        }
        Wt[id] = v;
    } else if (id < NFEAT * NOUT + NOUT) {
        int o = id - NFEAT * NOUT;
        float v;
        if (o < 9) v = mask_b[o];
        else {
            int oo = o - 9, i = oo / 18, j = oo % 18;
            v = off_b[i * 18 + j] + PTS[j] * (float)(2 * i + 1);
        }
        bias[o] = v;
    }
}

// ---------------------------------------------------------------------------
// Kernel 1: per-pixel 192-feature x 81-output linear map (the fused convs).
// ---------------------------------------------------------------------------
__global__ __launch_bounds__(256) void conv_offsets(
    const float* __restrict__ x,     // (2,64,256,256)
    const float* __restrict__ Wt,    // (192,81)
    const float* __restrict__ bias,  // (81,)
    float* __restrict__ mask_ws,     // (2,9,HW)
    float* __restrict__ off_ws)      // (2,72,HW)
{
    int gid = blockIdx.x * 256 + threadIdx.x;   // 131072 threads
    int b = gid >> 16;
    int pix = gid & 65535;
    int h = pix >> 8, w = pix & 255;

    float acc[NOUT];
#pragma unroll
    for (int o = 0; o < NOUT; ++o) acc[o] = bias[o];

    const float* xb = x + (size_t)b * 64 * HW;

    for (int p = 0; p < 9; ++p) {
        int hh = h + p / 3 - 1;
        int ww = w + p % 3 - 1;
        bool valid = ((unsigned)hh < 256u) && ((unsigned)ww < 256u);
        int poff = hh * 256 + ww;
        const float* wbase = Wt + p * 16 * NOUT;
        for (int c = 0; c < 16; ++c) {
            float xv = 0.f;
            if (valid) xv = xb[c * HW + poff];
            const float* wr = wbase + c * NOUT;
#pragma unroll
            for (int o = 0; o < NOUT; ++o) acc[o] = fmaf(xv, wr[o], acc[o]);
        }
    }
    for (int c = 0; c < 48; ++c) {
        float xv = xb[(16 + c) * HW + pix];
        const float* wr = Wt + (144 + c) * NOUT;
#pragma unroll
        for (int o = 0; o < NOUT; ++o) acc[o] = fmaf(xv, wr[o], acc[o]);
    }

#pragma unroll
    for (int k = 0; k < 9; ++k)
        mask_ws[(b * 9 + k) * HW + pix] = acc[k];
#pragma unroll
    for (int t = 0; t < 72; ++t)
        off_ws[(b * 72 + t) * HW + pix] = acc[9 + t];
}

// ---------------------------------------------------------------------------
// Transpose y (4,64,HW) -> T[(t*8+z)][pix][16c]  (channels innermost, 64B units)
// ---------------------------------------------------------------------------
__global__ __launch_bounds__(256) void transpose_y(
    const float* __restrict__ y, float* __restrict__ T)
{
    int bid = blockIdx.x;            // 2048
    int z = bid & 7, pr = bid >> 3;
    int pix = pr * 256 + threadIdx.x;
    int xb = z >> 2, i = z & 3;

    const float* p1 = y + (size_t)(xb * 64 + i * 16) * HW + pix;
    const float* p2 = y + (size_t)((xb + 2) * 64 + i * 16) * HW + pix;

    float v[16];
#pragma unroll
    for (int c = 0; c < 16; ++c) v[c] = p1[(size_t)c * HW];
    float4* dst = (float4*)(T + ((size_t)z * HW + pix) * 16);
#pragma unroll
    for (int j = 0; j < 4; ++j)
        dst[j] = make_float4(v[4 * j], v[4 * j + 1], v[4 * j + 2], v[4 * j + 3]);

#pragma unroll
    for (int c = 0; c < 16; ++c) v[c] = p2[(size_t)c * HW];
    dst = (float4*)(T + ((size_t)(8 + z) * HW + pix) * 16);
#pragma unroll
    for (int j = 0; j < 4; ++j)
        dst[j] = make_float4(v[4 * j], v[4 * j + 1], v[4 * j + 2], v[4 * j + 3]);
}

// ---------------------------------------------------------------------------
// Kernel 2 v3: block = (z [XCD-pinned], t, h); thread = w; k-loop in-thread.
// off/mask for all 9 k hoisted before the loop (chain depth 1+9 gathers).
// Per k: 16 float4 gathers into registers, bilinear FMA, 16 strided stores.
// ---------------------------------------------------------------------------
__global__ __launch_bounds__(256) void warp_apply_t(
    const float* __restrict__ T,        // (16,HW,16)
    const float* __restrict__ mask_ws,  // (2,9,HW)
    const float* __restrict__ off_ws,   // (2,72,HW)
    float* __restrict__ out)            // (4,64,9,256,256)
{
    int bid = blockIdx.x;            // 4096
    int z = bid & 7;
    int r = bid >> 3;                // 0..511
    int t = r >> 8;                  // 0..1
    int h = r & 255;
    int w = threadIdx.x;
    int pix = h * 256 + w;
    int xb = z >> 2, i = z & 3;

    const float* Tt = T + (size_t)(t * 8 + z) * HW * 16;

    // hoist all per-k scalars (27 coalesced loads, independent)
    float oxv[9], oyv[9], mv[9];
#pragma unroll
    for (int k = 0; k < 9; ++k) {
        oxv[k] = off_ws[(size_t)(z * 18 + 2 * k) * HW + pix];
        oyv[k] = off_ws[(size_t)(z * 18 + 2 * k + 1) * HW + pix];
        mv[k]  = mask_ws[(size_t)(xb * 9 + k) * HW + pix];
    }

    float* obase = out + (size_t)((xb + 2 * t) * 64 + i * 16) * 9 * HW + pix;

#pragma unroll 1
    for (int k = 0; k < 9; ++k) {
        float m = mv[k];
        float px = fminf(fmaxf((float)w + oxv[k], 0.f), 255.f);
        float py = fminf(fmaxf((float)h + oyv[k], 0.f), 255.f);
        float x0f = floorf(px), y0f = floorf(py);
        float wx = px - x0f, wy = py - y0f;
        int x0 = (int)x0f, y0 = (int)y0f;
        int x1 = min(x0 + 1, 255), y1 = min(y0 + 1, 255);

        float w00 = (1.f - wx) * (1.f - wy) * m;
        float w01 = wx * (1.f - wy) * m;
        float w10 = (1.f - wx) * wy * m;
        float w11 = wx * wy * m;

        const float4* A = (const float4*)(Tt + (size_t)(y0 * 256 + x0) * 16);
        const float4* B = (const float4*)(Tt + (size_t)(y0 * 256 + x1) * 16);
        const float4* C = (const float4*)(Tt + (size_t)(y1 * 256 + x0) * 16);
        const float4* D = (const float4*)(Tt + (size_t)(y1 * 256 + x1) * 16);

        // all 16 loads issued before consumption -> max MLP
        float4 va0 = A[0], va1 = A[1], va2 = A[2], va3 = A[3];
        float4 vb0 = B[0], vb1 = B[1], vb2 = B[2], vb3 = B[3];
        float4 vc0 = C[0], vc1 = C[1], vc2 = C[2], vc3 = C[3];
        float4 vd0 = D[0], vd1 = D[1], vd2 = D[2], vd3 = D[3];

        float acc[16];
        {
            const float4 a[4] = {va0, va1, va2, va3};
            const float4 b[4] = {vb0, vb1, vb2, vb3};
            const float4 c[4] = {vc0, vc1, vc2, vc3};
            const float4 d[4] = {vd0, vd1, vd2, vd3};
#pragma unroll
            for (int j = 0; j < 4; ++j) {
                acc[4*j]   = w00 * a[j].x; acc[4*j+1] = w00 * a[j].y;
                acc[4*j+2] = w00 * a[j].z; acc[4*j+3] = w00 * a[j].w;
            }
#pragma unroll
            for (int j = 0; j < 4; ++j) {
                acc[4*j]   = fmaf(w01, b[j].x, acc[4*j]);
                acc[4*j+1] = fmaf(w01, b[j].y, acc[4*j+1]);
                acc[4*j+2] = fmaf(w01, b[j].z, acc[4*j+2]);
                acc[4*j+3] = fmaf(w01, b[j].w, acc[4*j+3]);
            }
#pragma unroll
            for (int j = 0; j < 4; ++j) {
                acc[4*j]   = fmaf(w10, c[j].x, acc[4*j]);
                acc[4*j+1] = fmaf(w10, c[j].y, acc[4*j+1]);
                acc[4*j+2] = fmaf(w10, c[j].z, acc[4*j+2]);
                acc[4*j+3] = fmaf(w10, c[j].w, acc[4*j+3]);
            }
#pragma unroll
            for (int j = 0; j < 4; ++j) {
                acc[4*j]   = fmaf(w11, d[j].x, acc[4*j]);
                acc[4*j+1] = fmaf(w11, d[j].y, acc[4*j+1]);
                acc[4*j+2] = fmaf(w11, d[j].z, acc[4*j+2]);
                acc[4*j+3] = fmaf(w11, d[j].w, acc[4*j+3]);
            }
        }

        float* ob = obase + (size_t)k * HW;
#pragma unroll
        for (int c = 0; c < 16; ++c)
            ob[(size_t)c * 9 * HW] = acc[c];
    }
}

// ---------------------------------------------------------------------------
// Fallback (round-2 kernel) if workspace too small for T.
// ---------------------------------------------------------------------------
__global__ __launch_bounds__(256) void warp_apply(
    const float* __restrict__ y,
    const float* __restrict__ mask_ws,
    const float* __restrict__ off_ws,
    float* __restrict__ out)
{
    int w = threadIdx.x;
    int h = blockIdx.x;
    int k = blockIdx.y;
    int z = blockIdx.z;
    int xb = z >> 2, i = z & 3;
    int pix = h * 256 + w;

    float ox = off_ws[(size_t)(z * 18 + 2 * k) * HW + pix];
    float oy = off_ws[(size_t)(z * 18 + 2 * k + 1) * HW + pix];
    float m  = mask_ws[(size_t)(xb * 9 + k) * HW + pix];

    float px = fminf(fmaxf((float)w + ox, 0.f), 255.f);
    float py = fminf(fmaxf((float)h + oy, 0.f), 255.f);
    float x0f = floorf(px), y0f = floorf(py);
    float wx = px - x0f, wy = py - y0f;
    int x0 = (int)x0f, y0 = (int)y0f;
    int x1 = min(x0 + 1, 255), y1 = min(y0 + 1, 255);

    float w00 = (1.f - wx) * (1.f - wy) * m;
    float w01 = wx * (1.f - wy) * m;
    float w10 = (1.f - wx) * wy * m;
    float w11 = wx * wy * m;

    int o00 = y0 * 256 + x0, o01 = y0 * 256 + x1;
    int o10 = y1 * 256 + x0, o11 = y1 * 256 + x1;

    const float* p1 = y + (size_t)(xb * 64 + i * 16) * HW;
    const float* p2 = y + (size_t)((xb + 2) * 64 + i * 16) * HW;
    float* out1 = out + ((size_t)(xb * 64 + i * 16) * 9 + k) * HW + pix;
    float* out2 = out + ((size_t)((xb + 2) * 64 + i * 16) * 9 + k) * HW + pix;

#pragma unroll
    for (int c = 0; c < 16; ++c) {
        const float* q = p1 + (size_t)c * HW;
        float v = w00 * q[o00] + w01 * q[o01] + w10 * q[o10] + w11 * q[o11];
        out1[(size_t)c * 9 * HW] = v;
        q = p2 + (size_t)c * HW;
        v = w00 * q[o00] + w01 * q[o01] + w10 * q[o10] + w11 * q[o11];
        out2[(size_t)c * 9 * HW] = v;
    }
}

// ---------------------------------------------------------------------------
extern "C" void kernel_launch(void* const* d_in, const int* in_sizes, int n_in,
                              void* d_out, int out_size, void* d_ws, size_t ws_size,
                              hipStream_t stream) {
    const float* x            = (const float*)d_in[0];
    const float* y            = (const float*)d_in[1];
    const float* off_pconv_w  = (const float*)d_in[2];
    const float* off_w        = (const float*)d_in[3];
    const float* off_b        = (const float*)d_in[4];
    const float* mask_pconv_w = (const float*)d_in[5];
    const float* mask_w       = (const float*)d_in[6];
    const float* mask_b       = (const float*)d_in[7];
    float* out = (float*)d_out;

    // ws layout (f32): [Wt+bias: 64KB] [mask: 4.7MB] [off: 37.7MB] [T: 67.1MB]
    float* Wt      = (float*)d_ws;
    float* bias    = Wt + NFEAT * NOUT;
    float* mask_ws = (float*)((char*)d_ws + 65536);
    float* off_ws  = mask_ws + (size_t)2 * 9 * HW;
    float* T       = off_ws + (size_t)2 * 72 * HW;

    size_t need = 65536 + (size_t)2 * 9 * HW * 4 + (size_t)2 * 72 * HW * 4
                + (size_t)16 * HW * 16 * 4;

    setup_weights<<<62, 256, 0, stream>>>(off_pconv_w, off_w, off_b,
                                          mask_pconv_w, mask_w, mask_b, Wt, bias);
    conv_offsets<<<512, 256, 0, stream>>>(x, Wt, bias, mask_ws, off_ws);

    if (ws_size >= need) {
        transpose_y<<<2048, 256, 0, stream>>>(y, T);
        warp_apply_t<<<4096, 256, 0, stream>>>(T, mask_ws, off_ws, out);
    } else {
        dim3 g2(256, 9, 8);
        warp_apply<<<g2, 256, 0, stream>>>(y, mask_ws, off_ws, out);
    }
}

// Round 5
// 501.357 us; speedup vs baseline: 1.3137x; 1.2774x over previous
//
#include <hip/hip_runtime.h>

#define HW 65536
#define NOUT 81     // 9 mask + 4*18 off
#define NFEAT 192   // 144 patch + 48 passthrough

// ---------------------------------------------------------------------------
// Setup: collapse (conv3x3 -> 1x1) into a single 192->81 linear map.
// ---------------------------------------------------------------------------
__global__ __launch_bounds__(256) void setup_weights(
    const float* __restrict__ off_pconv_w,  // (4,16,16,3,3)
    const float* __restrict__ off_w,        // (4,18,64)
    const float* __restrict__ off_b,        // (4,18)
    const float* __restrict__ mask_pconv_w, // (16,16,3,3)
    const float* __restrict__ mask_w,       // (9,64)
    const float* __restrict__ mask_b,       // (9,)
    float* __restrict__ Wt,                 // (192,81)
    float* __restrict__ bias)               // (81,)
{
    int id = blockIdx.x * 256 + threadIdx.x;
    const float PTS[18] = {-1,-1, -1,0, -1,1, 0,-1, 0,0, 0,1, 1,-1, 1,0, 1,1};
    if (id < NFEAT * NOUT) {
        int f = id / NOUT;
        int o = id % NOUT;
        float v;
        if (f < 144) {
            int p = f >> 4, c = f & 15;
            float s = 0.f;
            if (o < 9) {
                for (int cm = 0; cm < 16; ++cm)
                    s += mask_w[o * 64 + cm] * mask_pconv_w[(cm * 16 + c) * 9 + p];
            } else {
                int oo = o - 9, i = oo / 18, j = oo % 18;
                for (int cm = 0; cm < 16; ++cm)
                    s += off_w[(i * 18 + j) * 64 + cm] * off_pconv_w[((i * 16 + cm) * 16 + c) * 9 + p];
            }
            v = s;
        } else {
            int c = f - 144;
            if (o < 9) v = mask_w[o * 64 + 16 + c];
            else { int oo = o - 9, i = oo / 18, j = oo % 18; v = off_w[(i * 18 + j) * 64 + 16 + c]; }
        }
        Wt[id] = v;
    } else if (id < NFEAT * NOUT + NOUT) {
        int o = id - NFEAT * NOUT;
        float v;
        if (o < 9) v = mask_b[o];
        else {
            int oo = o - 9, i = oo / 18, j = oo % 18;
            v = off_b[i * 18 + j] + PTS[j] * (float)(2 * i + 1);
        }
        bias[o] = v;
    }
}

// ---------------------------------------------------------------------------
// Kernel 1: per-pixel 192-feature x 81-output linear map (the fused convs).
// ---------------------------------------------------------------------------
__global__ __launch_bounds__(256) void conv_offsets(
    const float* __restrict__ x,     // (2,64,256,256)
    const float* __restrict__ Wt,    // (192,81)
    const float* __restrict__ bias,  // (81,)
    float* __restrict__ mask_ws,     // (2,9,HW)
    float* __restrict__ off_ws)      // (2,72,HW)
{
    int gid = blockIdx.x * 256 + threadIdx.x;   // 131072 threads
    int b = gid >> 16;
    int pix = gid & 65535;
    int h = pix >> 8, w = pix & 255;

    float acc[NOUT];
#pragma unroll
    for (int o = 0; o < NOUT; ++o) acc[o] = bias[o];

    const float* xb = x + (size_t)b * 64 * HW;

    for (int p = 0; p < 9; ++p) {
        int hh = h + p / 3 - 1;
        int ww = w + p % 3 - 1;
        bool valid = ((unsigned)hh < 256u) && ((unsigned)ww < 256u);
        int poff = hh * 256 + ww;
        const float* wbase = Wt + p * 16 * NOUT;
        for (int c = 0; c < 16; ++c) {
            float xv = 0.f;
            if (valid) xv = xb[c * HW + poff];
            const float* wr = wbase + c * NOUT;
#pragma unroll
            for (int o = 0; o < NOUT; ++o) acc[o] = fmaf(xv, wr[o], acc[o]);
        }
    }
    for (int c = 0; c < 48; ++c) {
        float xv = xb[(16 + c) * HW + pix];
        const float* wr = Wt + (144 + c) * NOUT;
#pragma unroll
        for (int o = 0; o < NOUT; ++o) acc[o] = fmaf(xv, wr[o], acc[o]);
    }

#pragma unroll
    for (int k = 0; k < 9; ++k)
        mask_ws[(b * 9 + k) * HW + pix] = acc[k];
#pragma unroll
    for (int t = 0; t < 72; ++t)
        off_ws[(b * 72 + t) * HW + pix] = acc[9 + t];
}

// ---------------------------------------------------------------------------
// Transpose y (4,64,HW) -> T[(t*8+z)][pix][16c]  (channels innermost, 64B rows)
// ---------------------------------------------------------------------------
__global__ __launch_bounds__(256) void transpose_y(
    const float* __restrict__ y, float* __restrict__ T)
{
    int bid = blockIdx.x;            // 2048
    int z = bid & 7, pr = bid >> 3;
    int pix = pr * 256 + threadIdx.x;
    int xb = z >> 2, i = z & 3;

    const float* p1 = y + (size_t)(xb * 64 + i * 16) * HW + pix;
    const float* p2 = y + (size_t)((xb + 2) * 64 + i * 16) * HW + pix;

    float v[16];
#pragma unroll
    for (int c = 0; c < 16; ++c) v[c] = p1[(size_t)c * HW];
    float4* dst = (float4*)(T + ((size_t)z * HW + pix) * 16);
#pragma unroll
    for (int j = 0; j < 4; ++j)
        dst[j] = make_float4(v[4 * j], v[4 * j + 1], v[4 * j + 2], v[4 * j + 3]);

#pragma unroll
    for (int c = 0; c < 16; ++c) v[c] = p2[(size_t)c * HW];
    dst = (float4*)(T + ((size_t)(8 + z) * HW + pix) * 16);
#pragma unroll
    for (int j = 0; j < 4; ++j)
        dst[j] = make_float4(v[4 * j], v[4 * j + 1], v[4 * j + 2], v[4 * j + 3]);
}

// ---------------------------------------------------------------------------
// Kernel 2 v4: thread = (pixel, c4); lanes 0..3 of a pixel-quad read the SAME
// 64B T-row (4 consecutive float4 sectors) -> 16 distinct lines per gather
// instr instead of 64. Per k: 4 gathers + 4 stores per thread.
// grid: bid = ((t*256+h)*4+wc)*8+z   (z in low bits -> XCD-pinned slices)
// ---------------------------------------------------------------------------
__global__ __launch_bounds__(256) void warp_apply_q(
    const float* __restrict__ T,        // (16,HW,16)
    const float* __restrict__ mask_ws,  // (2,9,HW)
    const float* __restrict__ off_ws,   // (2,72,HW)
    float* __restrict__ out)            // (4,64,9,256,256)
{
    int bid = blockIdx.x;            // 16384
    int z  = bid & 7;
    int wc = (bid >> 3) & 3;
    int h  = (bid >> 5) & 255;
    int t  = bid >> 13;
    int c4 = threadIdx.x & 3;
    int pl = threadIdx.x >> 2;       // 0..63
    int w  = wc * 64 + pl;
    int pix = h * 256 + w;
    int xb = z >> 2, i = z & 3;

    const float* Tt = T + (size_t)(t * 8 + z) * HW * 16;

    // hoist all per-k scalars (27 loads; lanes 0..3 broadcast-duplicate)
    float oxv[9], oyv[9], mv[9];
#pragma unroll
    for (int k = 0; k < 9; ++k) {
        oxv[k] = off_ws[(size_t)(z * 18 + 2 * k) * HW + pix];
        oyv[k] = off_ws[(size_t)(z * 18 + 2 * k + 1) * HW + pix];
        mv[k]  = mask_ws[(size_t)(xb * 9 + k) * HW + pix];
    }

    // channel base for this thread: c = i*16 + c4*4 + j
    float* obase = out + ((size_t)((xb + 2 * t) * 64 + i * 16 + c4 * 4)) * 9 * HW + pix;
    int sec = c4 * 4;   // float offset of this lane's 16B sector within the row

#pragma unroll 1
    for (int k = 0; k < 9; ++k) {
        float m = mv[k];
        float px = fminf(fmaxf((float)w + oxv[k], 0.f), 255.f);
        float py = fminf(fmaxf((float)h + oyv[k], 0.f), 255.f);
        float x0f = floorf(px), y0f = floorf(py);
        float wx = px - x0f, wy = py - y0f;
        int x0 = (int)x0f, y0 = (int)y0f;
        int x1 = min(x0 + 1, 255), y1 = min(y0 + 1, 255);

        float w00 = (1.f - wx) * (1.f - wy) * m;
        float w01 = wx * (1.f - wy) * m;
        float w10 = (1.f - wx) * wy * m;
        float w11 = wx * wy * m;

        float4 va = *(const float4*)(Tt + (size_t)(y0 * 256 + x0) * 16 + sec);
        float4 vb = *(const float4*)(Tt + (size_t)(y0 * 256 + x1) * 16 + sec);
        float4 vc = *(const float4*)(Tt + (size_t)(y1 * 256 + x0) * 16 + sec);
        float4 vd = *(const float4*)(Tt + (size_t)(y1 * 256 + x1) * 16 + sec);

        float a0 = w00 * va.x, a1 = w00 * va.y, a2 = w00 * va.z, a3 = w00 * va.w;
        a0 = fmaf(w01, vb.x, a0); a1 = fmaf(w01, vb.y, a1);
        a2 = fmaf(w01, vb.z, a2); a3 = fmaf(w01, vb.w, a3);
        a0 = fmaf(w10, vc.x, a0); a1 = fmaf(w10, vc.y, a1);
        a2 = fmaf(w10, vc.z, a2); a3 = fmaf(w10, vc.w, a3);
        a0 = fmaf(w11, vd.x, a0); a1 = fmaf(w11, vd.y, a1);
        a2 = fmaf(w11, vd.z, a2); a3 = fmaf(w11, vd.w, a3);

        float* ob = obase + (size_t)k * HW;
        ob[0]                  = a0;
        ob[(size_t)9 * HW]     = a1;
        ob[(size_t)18 * HW]    = a2;
        ob[(size_t)27 * HW]    = a3;
    }
}

// ---------------------------------------------------------------------------
// Fallback (round-2 kernel) if workspace too small for T.
// ---------------------------------------------------------------------------
__global__ __launch_bounds__(256) void warp_apply(
    const float* __restrict__ y,
    const float* __restrict__ mask_ws,
    const float* __restrict__ off_ws,
    float* __restrict__ out)
{
    int w = threadIdx.x;
    int h = blockIdx.x;
    int k = blockIdx.y;
    int z = blockIdx.z;
    int xb = z >> 2, i = z & 3;
    int pix = h * 256 + w;

    float ox = off_ws[(size_t)(z * 18 + 2 * k) * HW + pix];
    float oy = off_ws[(size_t)(z * 18 + 2 * k + 1) * HW + pix];
    float m  = mask_ws[(size_t)(xb * 9 + k) * HW + pix];

    float px = fminf(fmaxf((float)w + ox, 0.f), 255.f);
    float py = fminf(fmaxf((float)h + oy, 0.f), 255.f);
    float x0f = floorf(px), y0f = floorf(py);
    float wx = px - x0f, wy = py - y0f;
    int x0 = (int)x0f, y0 = (int)y0f;
    int x1 = min(x0 + 1, 255), y1 = min(y0 + 1, 255);

    float w00 = (1.f - wx) * (1.f - wy) * m;
    float w01 = wx * (1.f - wy) * m;
    float w10 = (1.f - wx) * wy * m;
    float w11 = wx * wy * m;

    int o00 = y0 * 256 + x0, o01 = y0 * 256 + x1;
    int o10 = y1 * 256 + x0, o11 = y1 * 256 + x1;

    const float* p1 = y + (size_t)(xb * 64 + i * 16) * HW;
    const float* p2 = y + (size_t)((xb + 2) * 64 + i * 16) * HW;
    float* out1 = out + ((size_t)(xb * 64 + i * 16) * 9 + k) * HW + pix;
    float* out2 = out + ((size_t)((xb + 2) * 64 + i * 16) * 9 + k) * HW + pix;

#pragma unroll
    for (int c = 0; c < 16; ++c) {
        const float* q = p1 + (size_t)c * HW;
        float v = w00 * q[o00] + w01 * q[o01] + w10 * q[o10] + w11 * q[o11];
        out1[(size_t)c * 9 * HW] = v;
        q = p2 + (size_t)c * HW;
        v = w00 * q[o00] + w01 * q[o01] + w10 * q[o10] + w11 * q[o11];
        out2[(size_t)c * 9 * HW] = v;
    }
}

// ---------------------------------------------------------------------------
extern "C" void kernel_launch(void* const* d_in, const int* in_sizes, int n_in,
                              void* d_out, int out_size, void* d_ws, size_t ws_size,
                              hipStream_t stream) {
    const float* x            = (const float*)d_in[0];
    const float* y            = (const float*)d_in[1];
    const float* off_pconv_w  = (const float*)d_in[2];
    const float* off_w        = (const float*)d_in[3];
    const float* off_b        = (const float*)d_in[4];
    const float* mask_pconv_w = (const float*)d_in[5];
    const float* mask_w       = (const float*)d_in[6];
    const float* mask_b       = (const float*)d_in[7];
    float* out = (float*)d_out;

    // ws layout (f32): [Wt+bias: 64KB] [mask: 4.7MB] [off: 37.7MB] [T: 67.1MB]
    float* Wt      = (float*)d_ws;
    float* bias    = Wt + NFEAT * NOUT;
    float* mask_ws = (float*)((char*)d_ws + 65536);
    float* off_ws  = mask_ws + (size_t)2 * 9 * HW;
    float* T       = off_ws + (size_t)2 * 72 * HW;

    size_t need = 65536 + (size_t)2 * 9 * HW * 4 + (size_t)2 * 72 * HW * 4
                + (size_t)16 * HW * 16 * 4;

    setup_weights<<<62, 256, 0, stream>>>(off_pconv_w, off_w, off_b,
                                          mask_pconv_w, mask_w, mask_b, Wt, bias);
    conv_offsets<<<512, 256, 0, stream>>>(x, Wt, bias, mask_ws, off_ws);

    if (ws_size >= need) {
        transpose_y<<<2048, 256, 0, stream>>>(y, T);
        warp_apply_q<<<16384, 256, 0, stream>>>(T, mask_ws, off_ws, out);
    } else {
        dim3 g2(256, 9, 8);
        warp_apply<<<g2, 256, 0, stream>>>(y, mask_ws, off_ws, out);
    }
}

// Round 6
// 440.089 us; speedup vs baseline: 1.4965x; 1.1392x over previous
//
#include <hip/hip_runtime.h>

#define HW 65536
#define NOUT 81     // 9 mask + 4*18 off
#define NFEAT 192   // 144 patch + 48 passthrough

typedef unsigned short ushort_t;

__device__ __forceinline__ float bf2f(ushort_t u) {
    union { unsigned int i; float f; } v; v.i = ((unsigned int)u) << 16; return v.f;
}
__device__ __forceinline__ ushort_t f2bf(float f) {
    union { float f; unsigned int i; } v; v.f = f;
    unsigned int r = v.i + 0x7FFF + ((v.i >> 16) & 1);   // RNE
    return (ushort_t)(r >> 16);
}

// ---------------------------------------------------------------------------
// Setup: collapse (conv3x3 -> 1x1) into a single 192->81 linear map.
// ---------------------------------------------------------------------------
__global__ __launch_bounds__(256) void setup_weights(
    const float* __restrict__ off_pconv_w,  // (4,16,16,3,3)
    const float* __restrict__ off_w,        // (4,18,64)
    const float* __restrict__ off_b,        // (4,18)
    const float* __restrict__ mask_pconv_w, // (16,16,3,3)
    const float* __restrict__ mask_w,       // (9,64)
    const float* __restrict__ mask_b,       // (9,)
    float* __restrict__ Wt,                 // (192,81)
    float* __restrict__ bias)               // (81,)
{
    int id = blockIdx.x * 256 + threadIdx.x;
    const float PTS[18] = {-1,-1, -1,0, -1,1, 0,-1, 0,0, 0,1, 1,-1, 1,0, 1,1};
    if (id < NFEAT * NOUT) {
        int f = id / NOUT;
        int o = id % NOUT;
        float v;
        if (f < 144) {
            int p = f >> 4, c = f & 15;
            float s = 0.f;
            if (o < 9) {
                for (int cm = 0; cm < 16; ++cm)
                    s += mask_w[o * 64 + cm] * mask_pconv_w[(cm * 16 + c) * 9 + p];
            } else {
                int oo = o - 9, i = oo / 18, j = oo % 18;
                for (int cm = 0; cm < 16; ++cm)
                    s += off_w[(i * 18 + j) * 64 + cm] * off_pconv_w[((i * 16 + cm) * 16 + c) * 9 + p];
            }
            v = s;
        } else {
            int c = f - 144;
            if (o < 9) v = mask_w[o * 64 + 16 + c];
            else { int oo = o - 9, i = oo / 18, j = oo % 18; v = off_w[(i * 18 + j) * 64 + 16 + c]; }
        }
        Wt[id] = v;
    } else if (id < NFEAT * NOUT + NOUT) {
        int o = id - NFEAT * NOUT;
        float v;
        if (o < 9) v = mask_b[o];
        else {
            int oo = o - 9, i = oo / 18, j = oo % 18;
            v = off_b[i * 18 + j] + PTS[j] * (float)(2 * i + 1);
        }
        bias[o] = v;
    }
}

// ---------------------------------------------------------------------------
// Kernel 1: per-pixel 192-feature x 81-output linear map (the fused convs).
// ---------------------------------------------------------------------------
__global__ __launch_bounds__(256) void conv_offsets(
    const float* __restrict__ x,     // (2,64,256,256)
    const float* __restrict__ Wt,    // (192,81)
    const float* __restrict__ bias,  // (81,)
    float* __restrict__ mask_ws,     // (2,9,HW)
    float* __restrict__ off_ws)      // (2,72,HW)
{
    int gid = blockIdx.x * 256 + threadIdx.x;   // 131072 threads
    int b = gid >> 16;
    int pix = gid & 65535;
    int h = pix >> 8, w = pix & 255;

    float acc[NOUT];
#pragma unroll
    for (int o = 0; o < NOUT; ++o) acc[o] = bias[o];

    const float* xb = x + (size_t)b * 64 * HW;

    for (int p = 0; p < 9; ++p) {
        int hh = h + p / 3 - 1;
        int ww = w + p % 3 - 1;
        bool valid = ((unsigned)hh < 256u) && ((unsigned)ww < 256u);
        int poff = hh * 256 + ww;
        const float* wbase = Wt + p * 16 * NOUT;
        for (int c = 0; c < 16; ++c) {
            float xv = 0.f;
            if (valid) xv = xb[c * HW + poff];
            const float* wr = wbase + c * NOUT;
#pragma unroll
            for (int o = 0; o < NOUT; ++o) acc[o] = fmaf(xv, wr[o], acc[o]);
        }
    }
    for (int c = 0; c < 48; ++c) {
        float xv = xb[(16 + c) * HW + pix];
        const float* wr = Wt + (144 + c) * NOUT;
#pragma unroll
        for (int o = 0; o < NOUT; ++o) acc[o] = fmaf(xv, wr[o], acc[o]);
    }

#pragma unroll
    for (int k = 0; k < 9; ++k)
        mask_ws[(b * 9 + k) * HW + pix] = acc[k];
#pragma unroll
    for (int t = 0; t < 72; ++t)
        off_ws[(b * 72 + t) * HW + pix] = acc[9 + t];
}

// ---------------------------------------------------------------------------
// Transpose y (4,64,HW) f32 -> Tb[(t*8+z)][pix][16c] bf16 (32B rows).
// ---------------------------------------------------------------------------
__global__ __launch_bounds__(256) void transpose_y_b(
    const float* __restrict__ y, ushort_t* __restrict__ Tb)
{
    int bid = blockIdx.x;            // 2048
    int z = bid & 7, pr = bid >> 3;
    int pix = pr * 256 + threadIdx.x;
    int xb = z >> 2, i = z & 3;

    const float* p1 = y + (size_t)(xb * 64 + i * 16) * HW + pix;
    const float* p2 = y + (size_t)((xb + 2) * 64 + i * 16) * HW + pix;

    ushort_t v[16];
#pragma unroll
    for (int c = 0; c < 16; ++c) v[c] = f2bf(p1[(size_t)c * HW]);
    uint4* dst = (uint4*)(Tb + ((size_t)z * HW + pix) * 16);
    dst[0] = *(const uint4*)&v[0];
    dst[1] = *(const uint4*)&v[8];

#pragma unroll
    for (int c = 0; c < 16; ++c) v[c] = f2bf(p2[(size_t)c * HW]);
    dst = (uint4*)(Tb + ((size_t)(8 + z) * HW + pix) * 16);
    dst[0] = *(const uint4*)&v[0];
    dst[1] = *(const uint4*)&v[8];
}

// ---------------------------------------------------------------------------
// Kernel 2 v5: thread = (pixel, c4); lanes 0..3 of a pixel-quad read the SAME
// 32B bf16 T-row; horizontal bilinear neighbors (x0,x1) are consecutive 32B
// rows -> share one 64B line. Per k: 4x 8B gathers + 4 stores per thread.
// grid: bid = ((t*256+h)*4+wc)*8+z   (z in low bits -> XCD-pinned slices)
// ---------------------------------------------------------------------------
__global__ __launch_bounds__(256) void warp_apply_b(
    const ushort_t* __restrict__ Tb,    // (16,HW,16) bf16
    const float* __restrict__ mask_ws,  // (2,9,HW)
    const float* __restrict__ off_ws,   // (2,72,HW)
    float* __restrict__ out)            // (4,64,9,256,256)
{
    int bid = blockIdx.x;            // 16384
    int z  = bid & 7;
    int wc = (bid >> 3) & 3;
    int h  = (bid >> 5) & 255;
    int t  = bid >> 13;
    int c4 = threadIdx.x & 3;
    int pl = threadIdx.x >> 2;       // 0..63
    int w  = wc * 64 + pl;
    int pix = h * 256 + w;
    int xb = z >> 2, i = z & 3;

    const ushort_t* Tt = Tb + (size_t)(t * 8 + z) * HW * 16;

    // hoist all per-k scalars (27 loads; lanes 0..3 broadcast same address)
    float oxv[9], oyv[9], mv[9];
#pragma unroll
    for (int k = 0; k < 9; ++k) {
        oxv[k] = off_ws[(size_t)(z * 18 + 2 * k) * HW + pix];
        oyv[k] = off_ws[(size_t)(z * 18 + 2 * k + 1) * HW + pix];
        mv[k]  = mask_ws[(size_t)(xb * 9 + k) * HW + pix];
    }

    // channel base for this thread: c = i*16 + c4*4 + j
    float* obase = out + ((size_t)((xb + 2 * t) * 64 + i * 16 + c4 * 4)) * 9 * HW + pix;
    int sec = c4 * 4;   // ushort offset of this lane's 8B sector within the row

#pragma unroll 1
    for (int k = 0; k < 9; ++k) {
        float m = mv[k];
        float px = fminf(fmaxf((float)w + oxv[k], 0.f), 255.f);
        float py = fminf(fmaxf((float)h + oyv[k], 0.f), 255.f);
        float x0f = floorf(px), y0f = floorf(py);
        float wx = px - x0f, wy = py - y0f;
        int x0 = (int)x0f, y0 = (int)y0f;
        int x1 = min(x0 + 1, 255), y1 = min(y0 + 1, 255);

        float w00 = (1.f - wx) * (1.f - wy) * m;
        float w01 = wx * (1.f - wy) * m;
        float w10 = (1.f - wx) * wy * m;
        float w11 = wx * wy * m;

        ushort4 va = *(const ushort4*)(Tt + (size_t)(y0 * 256 + x0) * 16 + sec);
        ushort4 vb = *(const ushort4*)(Tt + (size_t)(y0 * 256 + x1) * 16 + sec);
        ushort4 vc = *(const ushort4*)(Tt + (size_t)(y1 * 256 + x0) * 16 + sec);
        ushort4 vd = *(const ushort4*)(Tt + (size_t)(y1 * 256 + x1) * 16 + sec);

        float a0 = w00 * bf2f(va.x), a1 = w00 * bf2f(va.y);
        float a2 = w00 * bf2f(va.z), a3 = w00 * bf2f(va.w);
        a0 = fmaf(w01, bf2f(vb.x), a0); a1 = fmaf(w01, bf2f(vb.y), a1);
        a2 = fmaf(w01, bf2f(vb.z), a2); a3 = fmaf(w01, bf2f(vb.w), a3);
        a0 = fmaf(w10, bf2f(vc.x), a0); a1 = fmaf(w10, bf2f(vc.y), a1);
        a2 = fmaf(w10, bf2f(vc.z), a2); a3 = fmaf(w10, bf2f(vc.w), a3);
        a0 = fmaf(w11, bf2f(vd.x), a0); a1 = fmaf(w11, bf2f(vd.y), a1);
        a2 = fmaf(w11, bf2f(vd.z), a2); a3 = fmaf(w11, bf2f(vd.w), a3);

        float* ob = obase + (size_t)k * HW;
        ob[0]                  = a0;
        ob[(size_t)9 * HW]     = a1;
        ob[(size_t)18 * HW]    = a2;
        ob[(size_t)27 * HW]    = a3;
    }
}

// ---------------------------------------------------------------------------
// Fallback (round-2 kernel) if workspace too small for Tb.
// ---------------------------------------------------------------------------
__global__ __launch_bounds__(256) void warp_apply(
    const float* __restrict__ y,
    const float* __restrict__ mask_ws,
    const float* __restrict__ off_ws,
    float* __restrict__ out)
{
    int w = threadIdx.x;
    int h = blockIdx.x;
    int k = blockIdx.y;
    int z = blockIdx.z;
    int xb = z >> 2, i = z & 3;
    int pix = h * 256 + w;

    float ox = off_ws[(size_t)(z * 18 + 2 * k) * HW + pix];
    float oy = off_ws[(size_t)(z * 18 + 2 * k + 1) * HW + pix];
    float m  = mask_ws[(size_t)(xb * 9 + k) * HW + pix];

    float px = fminf(fmaxf((float)w + ox, 0.f), 255.f);
    float py = fminf(fmaxf((float)h + oy, 0.f), 255.f);
    float x0f = floorf(px), y0f = floorf(py);
    float wx = px - x0f, wy = py - y0f;
    int x0 = (int)x0f, y0 = (int)y0f;
    int x1 = min(x0 + 1, 255), y1 = min(y0 + 1, 255);

    float w00 = (1.f - wx) * (1.f - wy) * m;
    float w01 = wx * (1.f - wy) * m;
    float w10 = (1.f - wx) * wy * m;
    float w11 = wx * wy * m;

    int o00 = y0 * 256 + x0, o01 = y0 * 256 + x1;
    int o10 = y1 * 256 + x0, o11 = y1 * 256 + x1;

    const float* p1 = y + (size_t)(xb * 64 + i * 16) * HW;
    const float* p2 = y + (size_t)((xb + 2) * 64 + i * 16) * HW;
    float* out1 = out + ((size_t)(xb * 64 + i * 16) * 9 + k) * HW + pix;
    float* out2 = out + ((size_t)((xb + 2) * 64 + i * 16) * 9 + k) * HW + pix;

#pragma unroll
    for (int c = 0; c < 16; ++c) {
        const float* q = p1 + (size_t)c * HW;
        float v = w00 * q[o00] + w01 * q[o01] + w10 * q[o10] + w11 * q[o11];
        out1[(size_t)c * 9 * HW] = v;
        q = p2 + (size_t)c * HW;
        v = w00 * q[o00] + w01 * q[o01] + w10 * q[o10] + w11 * q[o11];
        out2[(size_t)c * 9 * HW] = v;
    }
}

// ---------------------------------------------------------------------------
extern "C" void kernel_launch(void* const* d_in, const int* in_sizes, int n_in,
                              void* d_out, int out_size, void* d_ws, size_t ws_size,
                              hipStream_t stream) {
    const float* x            = (const float*)d_in[0];
    const float* y            = (const float*)d_in[1];
    const float* off_pconv_w  = (const float*)d_in[2];
    const float* off_w        = (const float*)d_in[3];
    const float* off_b        = (const float*)d_in[4];
    const float* mask_pconv_w = (const float*)d_in[5];
    const float* mask_w       = (const float*)d_in[6];
    const float* mask_b       = (const float*)d_in[7];
    float* out = (float*)d_out;

    // ws layout: [Wt+bias: 64KB] [mask f32: 4.7MB] [off f32: 37.7MB] [Tb bf16: 33.5MB]
    float* Wt      = (float*)d_ws;
    float* bias    = Wt + NFEAT * NOUT;
    float* mask_ws = (float*)((char*)d_ws + 65536);
    float* off_ws  = mask_ws + (size_t)2 * 9 * HW;
    ushort_t* Tb   = (ushort_t*)(off_ws + (size_t)2 * 72 * HW);

    size_t need = 65536 + (size_t)2 * 9 * HW * 4 + (size_t)2 * 72 * HW * 4
                + (size_t)16 * HW * 16 * 2;

    setup_weights<<<62, 256, 0, stream>>>(off_pconv_w, off_w, off_b,
                                          mask_pconv_w, mask_w, mask_b, Wt, bias);
    conv_offsets<<<512, 256, 0, stream>>>(x, Wt, bias, mask_ws, off_ws);

    if (ws_size >= need) {
        transpose_y_b<<<2048, 256, 0, stream>>>(y, Tb);
        warp_apply_b<<<16384, 256, 0, stream>>>(Tb, mask_ws, off_ws, out);
    } else {
        dim3 g2(256, 9, 8);
        warp_apply<<<g2, 256, 0, stream>>>(y, mask_ws, off_ws, out);
    }
}

// Round 7
// 439.729 us; speedup vs baseline: 1.4978x; 1.0008x over previous
//
#include <hip/hip_runtime.h>

#define HW 65536
#define NOUT 81     // 9 mask + 4*18 off
#define NFEAT 192   // 144 patch + 48 passthrough
#define WROW 84     // padded LDS row stride (16B-aligned float4 rows)

typedef unsigned short ushort_t;

__device__ __forceinline__ float bf2f(ushort_t u) {
    union { unsigned int i; float f; } v; v.i = ((unsigned int)u) << 16; return v.f;
}
__device__ __forceinline__ ushort_t f2bf(float f) {
    union { float f; unsigned int i; } v; v.f = f;
    unsigned int r = v.i + 0x7FFF + ((v.i >> 16) & 1);   // RNE
    return (ushort_t)(r >> 16);
}

// ---------------------------------------------------------------------------
// Setup: collapse (conv3x3 -> 1x1) into a single 192->81 linear map.
// ---------------------------------------------------------------------------
__global__ __launch_bounds__(256) void setup_weights(
    const float* __restrict__ off_pconv_w,  // (4,16,16,3,3)
    const float* __restrict__ off_w,        // (4,18,64)
    const float* __restrict__ off_b,        // (4,18)
    const float* __restrict__ mask_pconv_w, // (16,16,3,3)
    const float* __restrict__ mask_w,       // (9,64)
    const float* __restrict__ mask_b,       // (9,)
    float* __restrict__ Wt,                 // (192,81)
    float* __restrict__ bias)               // (81,)
{
    int id = blockIdx.x * 256 + threadIdx.x;
    const float PTS[18] = {-1,-1, -1,0, -1,1, 0,-1, 0,0, 0,1, 1,-1, 1,0, 1,1};
    if (id < NFEAT * NOUT) {
        int f = id / NOUT;
        int o = id % NOUT;
        float v;
        if (f < 144) {
            int p = f >> 4, c = f & 15;
            float s = 0.f;
            if (o < 9) {
                for (int cm = 0; cm < 16; ++cm)
                    s += mask_w[o * 64 + cm] * mask_pconv_w[(cm * 16 + c) * 9 + p];
            } else {
                int oo = o - 9, i = oo / 18, j = oo % 18;
                for (int cm = 0; cm < 16; ++cm)
                    s += off_w[(i * 18 + j) * 64 + cm] * off_pconv_w[((i * 16 + cm) * 16 + c) * 9 + p];
            }
            v = s;
        } else {
            int c = f - 144;
            if (o < 9) v = mask_w[o * 64 + 16 + c];
            else { int oo = o - 9, i = oo / 18, j = oo % 18; v = off_w[(i * 18 + j) * 64 + 16 + c]; }
        }
        Wt[id] = v;
    } else if (id < NFEAT * NOUT + NOUT) {
        int o = id - NFEAT * NOUT;
        float v;
        if (o < 9) v = mask_b[o];
        else {
            int oo = o - 9, i = oo / 18, j = oo % 18;
            v = off_b[i * 18 + j] + PTS[j] * (float)(2 * i + 1);
        }
        bias[o] = v;
    }
}

// ---------------------------------------------------------------------------
// Kernel 1 v2: weights staged in LDS (Wt is 62KB > 32KB L1 -> global-load
// version thrashed L1 and stalled on vmcnt). ds_read_b128 broadcast reads
// run on the LDS pipe, overlapping the 81-wide FMA stream.
// ---------------------------------------------------------------------------
__global__ __launch_bounds__(512) void conv_offsets_lds(
    const float* __restrict__ x,     // (2,64,256,256)
    const float* __restrict__ Wt,    // (192,81)
    const float* __restrict__ bias,  // (81,)
    float* __restrict__ mask_ws,     // (2,9,HW)
    float* __restrict__ off_ws)      // (2,72,HW)
{
    __shared__ float wl[NFEAT * WROW + NOUT];
    int tid = threadIdx.x;
    for (int idx = tid; idx < NFEAT * NOUT; idx += 512)
        wl[(idx / NOUT) * WROW + (idx % NOUT)] = Wt[idx];
    if (tid < NOUT) wl[NFEAT * WROW + tid] = bias[tid];
    __syncthreads();

    int gid = blockIdx.x * 512 + tid;   // 131072 threads, 256 blocks
    int b = gid >> 16;
    int pix = gid & 65535;
    int h = pix >> 8, w = pix & 255;

    float acc[NOUT];
#pragma unroll
    for (int o = 0; o < NOUT; ++o) acc[o] = wl[NFEAT * WROW + o];

    const float* xb = x + (size_t)b * 64 * HW;

    for (int p = 0; p < 9; ++p) {
        int hh = h + p / 3 - 1;
        int ww = w + p % 3 - 1;
        bool valid = ((unsigned)hh < 256u) && ((unsigned)ww < 256u);
        int poff = hh * 256 + ww;
        for (int c = 0; c < 16; ++c) {
            float xv = 0.f;
            if (valid) xv = xb[c * HW + poff];
            const float* wr = &wl[(p * 16 + c) * WROW];
#pragma unroll
            for (int j = 0; j < 20; ++j) {
                float4 w4 = *(const float4*)(wr + 4 * j);
                acc[4*j]   = fmaf(xv, w4.x, acc[4*j]);
                acc[4*j+1] = fmaf(xv, w4.y, acc[4*j+1]);
                acc[4*j+2] = fmaf(xv, w4.z, acc[4*j+2]);
                acc[4*j+3] = fmaf(xv, w4.w, acc[4*j+3]);
            }
            acc[80] = fmaf(xv, wr[80], acc[80]);
        }
    }
    for (int c = 0; c < 48; ++c) {
        float xv = xb[(16 + c) * HW + pix];
        const float* wr = &wl[(144 + c) * WROW];
#pragma unroll
        for (int j = 0; j < 20; ++j) {
            float4 w4 = *(const float4*)(wr + 4 * j);
            acc[4*j]   = fmaf(xv, w4.x, acc[4*j]);
            acc[4*j+1] = fmaf(xv, w4.y, acc[4*j+1]);
            acc[4*j+2] = fmaf(xv, w4.z, acc[4*j+2]);
            acc[4*j+3] = fmaf(xv, w4.w, acc[4*j+3]);
        }
        acc[80] = fmaf(xv, wr[80], acc[80]);
    }

#pragma unroll
    for (int k = 0; k < 9; ++k)
        mask_ws[(b * 9 + k) * HW + pix] = acc[k];
#pragma unroll
    for (int t = 0; t < 72; ++t)
        off_ws[(b * 72 + t) * HW + pix] = acc[9 + t];
}

// ---------------------------------------------------------------------------
// Transpose y (4,64,HW) f32 -> Tb[(t*8+z)][pix][16c] bf16 (32B rows).
// ---------------------------------------------------------------------------
__global__ __launch_bounds__(256) void transpose_y_b(
    const float* __restrict__ y, ushort_t* __restrict__ Tb)
{
    int bid = blockIdx.x;            // 2048
    int z = bid & 7, pr = bid >> 3;
    int pix = pr * 256 + threadIdx.x;
    int xb = z >> 2, i = z & 3;

    const float* p1 = y + (size_t)(xb * 64 + i * 16) * HW + pix;
    const float* p2 = y + (size_t)((xb + 2) * 64 + i * 16) * HW + pix;

    ushort_t v[16];
#pragma unroll
    for (int c = 0; c < 16; ++c) v[c] = f2bf(p1[(size_t)c * HW]);
    uint4* dst = (uint4*)(Tb + ((size_t)z * HW + pix) * 16);
    dst[0] = *(const uint4*)&v[0];
    dst[1] = *(const uint4*)&v[8];

#pragma unroll
    for (int c = 0; c < 16; ++c) v[c] = f2bf(p2[(size_t)c * HW]);
    dst = (uint4*)(Tb + ((size_t)(8 + z) * HW + pix) * 16);
    dst[0] = *(const uint4*)&v[0];
    dst[1] = *(const uint4*)&v[8];
}

// ---------------------------------------------------------------------------
// Kernel 2 v5: thread = (pixel, c4); lanes 0..3 of a pixel-quad read the SAME
// 32B bf16 T-row; horizontal bilinear neighbors (x0,x1) are consecutive 32B
// rows -> share one 64B line. Per k: 4x 8B gathers + 4 stores per thread.
// ---------------------------------------------------------------------------
__global__ __launch_bounds__(256) void warp_apply_b(
    const ushort_t* __restrict__ Tb,    // (16,HW,16) bf16
    const float* __restrict__ mask_ws,  // (2,9,HW)
    const float* __restrict__ off_ws,   // (2,72,HW)
    float* __restrict__ out)            // (4,64,9,256,256)
{
    int bid = blockIdx.x;            // 16384
    int z  = bid & 7;
    int wc = (bid >> 3) & 3;
    int h  = (bid >> 5) & 255;
    int t  = bid >> 13;
    int c4 = threadIdx.x & 3;
    int pl = threadIdx.x >> 2;       // 0..63
    int w  = wc * 64 + pl;
    int pix = h * 256 + w;
    int xb = z >> 2, i = z & 3;

    const ushort_t* Tt = Tb + (size_t)(t * 8 + z) * HW * 16;

    float oxv[9], oyv[9], mv[9];
#pragma unroll
    for (int k = 0; k < 9; ++k) {
        oxv[k] = off_ws[(size_t)(z * 18 + 2 * k) * HW + pix];
        oyv[k] = off_ws[(size_t)(z * 18 + 2 * k + 1) * HW + pix];
        mv[k]  = mask_ws[(size_t)(xb * 9 + k) * HW + pix];
    }

    float* obase = out + ((size_t)((xb + 2 * t) * 64 + i * 16 + c4 * 4)) * 9 * HW + pix;
    int sec = c4 * 4;

#pragma unroll 1
    for (int k = 0; k < 9; ++k) {
        float m = mv[k];
        float px = fminf(fmaxf((float)w + oxv[k], 0.f), 255.f);
        float py = fminf(fmaxf((float)h + oyv[k], 0.f), 255.f);
        float x0f = floorf(px), y0f = floorf(py);
        float wx = px - x0f, wy = py - y0f;
        int x0 = (int)x0f, y0 = (int)y0f;
        int x1 = min(x0 + 1, 255), y1 = min(y0 + 1, 255);

        float w00 = (1.f - wx) * (1.f - wy) * m;
        float w01 = wx * (1.f - wy) * m;
        float w10 = (1.f - wx) * wy * m;
        float w11 = wx * wy * m;

        ushort4 va = *(const ushort4*)(Tt + (size_t)(y0 * 256 + x0) * 16 + sec);
        ushort4 vb = *(const ushort4*)(Tt + (size_t)(y0 * 256 + x1) * 16 + sec);
        ushort4 vc = *(const ushort4*)(Tt + (size_t)(y1 * 256 + x0) * 16 + sec);
        ushort4 vd = *(const ushort4*)(Tt + (size_t)(y1 * 256 + x1) * 16 + sec);

        float a0 = w00 * bf2f(va.x), a1 = w00 * bf2f(va.y);
        float a2 = w00 * bf2f(va.z), a3 = w00 * bf2f(va.w);
        a0 = fmaf(w01, bf2f(vb.x), a0); a1 = fmaf(w01, bf2f(vb.y), a1);
        a2 = fmaf(w01, bf2f(vb.z), a2); a3 = fmaf(w01, bf2f(vb.w), a3);
        a0 = fmaf(w10, bf2f(vc.x), a0); a1 = fmaf(w10, bf2f(vc.y), a1);
        a2 = fmaf(w10, bf2f(vc.z), a2); a3 = fmaf(w10, bf2f(vc.w), a3);
        a0 = fmaf(w11, bf2f(vd.x), a0); a1 = fmaf(w11, bf2f(vd.y), a1);
        a2 = fmaf(w11, bf2f(vd.z), a2); a3 = fmaf(w11, bf2f(vd.w), a3);

        float* ob = obase + (size_t)k * HW;
        ob[0]                  = a0;
        ob[(size_t)9 * HW]     = a1;
        ob[(size_t)18 * HW]    = a2;
        ob[(size_t)27 * HW]    = a3;
    }
}

// ---------------------------------------------------------------------------
// Fallback (round-2 kernel) if workspace too small for Tb.
// ---------------------------------------------------------------------------
__global__ __launch_bounds__(256) void warp_apply(
    const float* __restrict__ y,
    const float* __restrict__ mask_ws,
    const float* __restrict__ off_ws,
    float* __restrict__ out)
{
    int w = threadIdx.x;
    int h = blockIdx.x;
    int k = blockIdx.y;
    int z = blockIdx.z;
    int xb = z >> 2, i = z & 3;
    int pix = h * 256 + w;

    float ox = off_ws[(size_t)(z * 18 + 2 * k) * HW + pix];
    float oy = off_ws[(size_t)(z * 18 + 2 * k + 1) * HW + pix];
    float m  = mask_ws[(size_t)(xb * 9 + k) * HW + pix];

    float px = fminf(fmaxf((float)w + ox, 0.f), 255.f);
    float py = fminf(fmaxf((float)h + oy, 0.f), 255.f);
    float x0f = floorf(px), y0f = floorf(py);
    float wx = px - x0f, wy = py - y0f;
    int x0 = (int)x0f, y0 = (int)y0f;
    int x1 = min(x0 + 1, 255), y1 = min(y0 + 1, 255);

    float w00 = (1.f - wx) * (1.f - wy) * m;
    float w01 = wx * (1.f - wy) * m;
    float w10 = (1.f - wx) * wy * m;
    float w11 = wx * wy * m;

    int o00 = y0 * 256 + x0, o01 = y0 * 256 + x1;
    int o10 = y1 * 256 + x0, o11 = y1 * 256 + x1;

    const float* p1 = y + (size_t)(xb * 64 + i * 16) * HW;
    const float* p2 = y + (size_t)((xb + 2) * 64 + i * 16) * HW;
    float* out1 = out + ((size_t)(xb * 64 + i * 16) * 9 + k) * HW + pix;
    float* out2 = out + ((size_t)((xb + 2) * 64 + i * 16) * 9 + k) * HW + pix;

#pragma unroll
    for (int c = 0; c < 16; ++c) {
        const float* q = p1 + (size_t)c * HW;
        float v = w00 * q[o00] + w01 * q[o01] + w10 * q[o10] + w11 * q[o11];
        out1[(size_t)c * 9 * HW] = v;
        q = p2 + (size_t)c * HW;
        v = w00 * q[o00] + w01 * q[o01] + w10 * q[o10] + w11 * q[o11];
        out2[(size_t)c * 9 * HW] = v;
    }
}

// ---------------------------------------------------------------------------
extern "C" void kernel_launch(void* const* d_in, const int* in_sizes, int n_in,
                              void* d_out, int out_size, void* d_ws, size_t ws_size,
                              hipStream_t stream) {
    const float* x            = (const float*)d_in[0];
    const float* y            = (const float*)d_in[1];
    const float* off_pconv_w  = (const float*)d_in[2];
    const float* off_w        = (const float*)d_in[3];
    const float* off_b        = (const float*)d_in[4];
    const float* mask_pconv_w = (const float*)d_in[5];
    const float* mask_w       = (const float*)d_in[6];
    const float* mask_b       = (const float*)d_in[7];
    float* out = (float*)d_out;

    // ws layout: [Wt+bias: 64KB] [mask f32: 4.7MB] [off f32: 37.7MB] [Tb bf16: 33.5MB]
    float* Wt      = (float*)d_ws;
    float* bias    = Wt + NFEAT * NOUT;
    float* mask_ws = (float*)((char*)d_ws + 65536);
    float* off_ws  = mask_ws + (size_t)2 * 9 * HW;
    ushort_t* Tb   = (ushort_t*)(off_ws + (size_t)2 * 72 * HW);

    size_t need = 65536 + (size_t)2 * 9 * HW * 4 + (size_t)2 * 72 * HW * 4
                + (size_t)16 * HW * 16 * 2;

    setup_weights<<<62, 256, 0, stream>>>(off_pconv_w, off_w, off_b,
                                          mask_pconv_w, mask_w, mask_b, Wt, bias);
    conv_offsets_lds<<<256, 512, 0, stream>>>(x, Wt, bias, mask_ws, off_ws);

    if (ws_size >= need) {
        transpose_y_b<<<2048, 256, 0, stream>>>(y, Tb);
        warp_apply_b<<<16384, 256, 0, stream>>>(Tb, mask_ws, off_ws, out);
    } else {
        dim3 g2(256, 9, 8);
        warp_apply<<<g2, 256, 0, stream>>>(y, mask_ws, off_ws, out);
    }
}